// Round 10
// baseline (513.805 us; speedup 1.0000x reference)
//
#include <hip/hip_runtime.h>

#define F 128
#define ROWS2 32
#define SCAN_TILE 1024
#define NCHUNK 8
#define CHUNKF 16       // floats per chunk (64 B)
#define TILE_NODES 64   // nodes per queue grab (4 waves x 16)

typedef float vfloat4 __attribute__((ext_vector_type(4)));  // clang-native for nontemporal builtins

__global__ void zero_int_kernel(int* __restrict__ p, int n) {
    int i = blockIdx.x * blockDim.x + threadIdx.x;
    if (i < n) p[i] = 0;
}

__global__ void zero_f4_kernel(float4* __restrict__ out, int n4) {
    int i = blockIdx.x * blockDim.x + threadIdx.x;
    if (i < n4) out[i] = make_float4(0.f, 0.f, 0.f, 0.f);
}

// wT[k][o] = W[o][k]
__global__ void transpose_w_kernel(const float* __restrict__ W, float* __restrict__ wT) {
    int i = blockIdx.x * 256 + threadIdx.x;
    int o = i >> 7, k = i & 127;
    wT[k * F + o] = W[i];
}

// featC[c][v][0..16) = feat[v][c*16 .. c*16+16)  — 8 slices of 3.2 MB
__global__ void reorder_feat_kernel(const float* __restrict__ feat,
                                    float* __restrict__ featC, int N) {
    int i = blockIdx.x * 256 + threadIdx.x;   // over N*32 float4s
    if (i >= N * 32) return;
    int v = i >> 5, j = i & 31;               // j: float4 index in row
    int c = j >> 2, qq = j & 3;
    float4 val = ((const float4*)feat)[i];
    ((float4*)featC)[((size_t)c * N + v) * 4 + qq] = val;
}

__global__ void hist_kernel(const int* __restrict__ dst, int* __restrict__ counts, int E) {
    int e = blockIdx.x * blockDim.x + threadIdx.x;
    if (e < E) atomicAdd(&counts[dst[e]], 1);
}

__global__ __launch_bounds__(256) void scan1_kernel(const int* __restrict__ counts,
                                                    int* __restrict__ offsets,
                                                    int* __restrict__ blockSums, int N) {
    __shared__ int lds[256];
    const int tid = threadIdx.x;
    const int i0 = blockIdx.x * SCAN_TILE + tid * 4;
    int v[4];
    int s = 0;
#pragma unroll
    for (int j = 0; j < 4; ++j) {
        int i = i0 + j;
        v[j] = (i < N) ? counts[i] : 0;
        s += v[j];
    }
    lds[tid] = s;
    __syncthreads();
    for (int off = 1; off < 256; off <<= 1) {
        int t = (tid >= off) ? lds[tid - off] : 0;
        __syncthreads();
        lds[tid] += t;
        __syncthreads();
    }
    int excl = lds[tid] - s;
#pragma unroll
    for (int j = 0; j < 4; ++j) {
        int i = i0 + j;
        if (i < N) offsets[i] = excl;
        excl += v[j];
    }
    if (tid == 255) blockSums[blockIdx.x] = lds[255];
}

// Also zeroes the 8 chunk-queue heads (if provided).
__global__ __launch_bounds__(256) void scan2_kernel(int* __restrict__ blockSums,
                                                    int* __restrict__ offsets,
                                                    int* __restrict__ qhead,
                                                    int NB, int N) {
    __shared__ int lds[256];
    const int tid = threadIdx.x;
    if (qhead && tid < NCHUNK) qhead[tid] = 0;
    int s = (tid < NB) ? blockSums[tid] : 0;
    lds[tid] = s;
    __syncthreads();
    for (int off = 1; off < 256; off <<= 1) {
        int t = (tid >= off) ? lds[tid - off] : 0;
        __syncthreads();
        lds[tid] += t;
        __syncthreads();
    }
    if (tid < NB) blockSums[tid] = lds[tid] - s;
    if (tid == 255) offsets[N] = lds[255];
}

__global__ __launch_bounds__(256) void scan3_kernel(int* __restrict__ offsets,
                                                    int* __restrict__ cursor,
                                                    const int* __restrict__ blockSums, int N) {
    int i = blockIdx.x * blockDim.x + threadIdx.x;
    if (i < N) {
        int o = offsets[i] + blockSums[i / SCAN_TILE];
        offsets[i] = o;
        cursor[i] = o;
    }
}

__global__ void place_kernel(const int* __restrict__ src, const int* __restrict__ dst,
                             int* __restrict__ cursor, int* __restrict__ ssrc, int E) {
    int e = blockIdx.x * blockDim.x + threadIdx.x;
    if (e < E) {
        int pos = atomicAdd(&cursor[dst[e]], 1);
        ssrc[pos] = src[e];
    }
}

// XCD-pinned chunked aggregation, MLP-restored edge loop.
// Lane map: lane = n2*16 + eidx*4 + q  (4 nodes || 4 contiguous-edge runs || 4 float4s).
// Per iteration each lane issues 4 ssrc loads + 4 INDEPENDENT gathers ->
// 16 gathers in flight per wave per node-group (R7-level MLP), while the
// slice (3.2 MB) stays resident in this XCD's L2.
__global__ __launch_bounds__(256) void agg_xcd_kernel(const float* __restrict__ featC,
                                                      const int* __restrict__ ssrc,
                                                      const int* __restrict__ offs,
                                                      int* __restrict__ qhead,
                                                      float* __restrict__ out, int N) {
    const int tid = threadIdx.x;
    const int wave = tid >> 6;
    const int lane = tid & 63;
    const int n2 = lane >> 4;
    const int eidx = (lane >> 2) & 3;
    const int q = lane & 3;
    const int ntiles = (N + TILE_NODES - 1) / TILE_NODES;

    // HW_REG_XCC_ID (id=20, offset=0, size=4) — perf heuristic only; stealing
    // below guarantees coverage regardless of what this returns.
    const int myxcd = (int)__builtin_amdgcn_s_getreg((3 << 11) | 20) & 7;

    __shared__ int s_tile;
    for (int pass = 0; pass < NCHUNK; ++pass) {
        const int c = (myxcd + pass) & 7;
        const vfloat4* slice = (const vfloat4*)(featC + (size_t)c * N * CHUNKF);
        float* outc = out + (size_t)c * CHUNKF;
        for (;;) {
            if (tid == 0) s_tile = atomicAdd(&qhead[c], 1);
            __syncthreads();
            const int tile = s_tile;
            __syncthreads();
            if (tile >= ntiles) break;
            const int base = tile * TILE_NODES + wave * 16 + n2;
            for (int g = 0; g < 16; g += 4) {
                const int node = base + g;
                vfloat4 acc = {0.f, 0.f, 0.f, 0.f};
                if (node < N) {
                    const int s0 = offs[node], s1 = offs[node + 1];
                    const int nfull = (s1 - s0) >> 4;   // 16-edge groups
                    int ebase = s0 + (eidx << 2);
                    for (int it = 0; it < nfull; ++it, ebase += 16) {
                        const int i0 = __builtin_nontemporal_load(&ssrc[ebase + 0]);
                        const int i1 = __builtin_nontemporal_load(&ssrc[ebase + 1]);
                        const int i2 = __builtin_nontemporal_load(&ssrc[ebase + 2]);
                        const int i3 = __builtin_nontemporal_load(&ssrc[ebase + 3]);
                        const vfloat4 f0 = slice[(size_t)i0 * 4 + q];
                        const vfloat4 f1 = slice[(size_t)i1 * 4 + q];
                        const vfloat4 f2 = slice[(size_t)i2 * 4 + q];
                        const vfloat4 f3 = slice[(size_t)i3 * 4 + q];
                        acc += (f0 + f1) + (f2 + f3);
                    }
                    for (int e = s0 + (nfull << 4) + eidx; e < s1; e += 4) {
                        const int i = __builtin_nontemporal_load(&ssrc[e]);
                        acc += slice[(size_t)i * 4 + q];
                    }
                }
                acc.x += __shfl_xor(acc.x, 4); acc.y += __shfl_xor(acc.y, 4);
                acc.z += __shfl_xor(acc.z, 4); acc.w += __shfl_xor(acc.w, 4);
                acc.x += __shfl_xor(acc.x, 8); acc.y += __shfl_xor(acc.y, 8);
                acc.z += __shfl_xor(acc.z, 8); acc.w += __shfl_xor(acc.w, 8);
                if (eidx == 0 && node < N) {
                    __builtin_nontemporal_store(acc, (vfloat4*)(outc + (size_t)node * F) + q);
                }
            }
        }
    }
}

// Tier-2 aggregation (R7): one wave per node, full rows.
__global__ __launch_bounds__(256) void agg_kernel(const float* __restrict__ feat,
                                                  const int* __restrict__ ssrc,
                                                  const int* __restrict__ offs,
                                                  float* __restrict__ out, int N) {
    const int gwave = (blockIdx.x * blockDim.x + threadIdx.x) >> 6;
    const int lane = threadIdx.x & 63;
    const int half = lane >> 5;
    const int q = lane & 31;
    const int nwaves = (gridDim.x * blockDim.x) >> 6;
    const float4* feat4 = (const float4*)feat;
    for (int v = gwave; v < N; v += nwaves) {
        const int s0 = offs[v], s1 = offs[v + 1];
        float ax = 0.f, ay = 0.f, az = 0.f, aw = 0.f;
        int e = s0 + half;
        for (; e + 6 < s1; e += 8) {
            int i0 = ssrc[e], i1 = ssrc[e + 2], i2 = ssrc[e + 4], i3 = ssrc[e + 6];
            const float4 f0 = feat4[(size_t)i0 * 32 + q];
            const float4 f1 = feat4[(size_t)i1 * 32 + q];
            const float4 f2 = feat4[(size_t)i2 * 32 + q];
            const float4 f3 = feat4[(size_t)i3 * 32 + q];
            ax += (f0.x + f1.x) + (f2.x + f3.x);
            ay += (f0.y + f1.y) + (f2.y + f3.y);
            az += (f0.z + f1.z) + (f2.z + f3.z);
            aw += (f0.w + f1.w) + (f2.w + f3.w);
        }
        for (; e < s1; e += 2) {
            const float4 f0 = feat4[(size_t)ssrc[e] * 32 + q];
            ax += f0.x; ay += f0.y; az += f0.z; aw += f0.w;
        }
        ax += __shfl_xor(ax, 32);
        ay += __shfl_xor(ay, 32);
        az += __shfl_xor(az, 32);
        aw += __shfl_xor(aw, 32);
        if (half == 0) {
            float4 r; r.x = ax; r.y = ay; r.z = az; r.w = aw;
            ((float4*)(out + (size_t)v * F))[q] = r;
        }
    }
}

// Tier-3 fallback: direct fp32 atomic scatter (R1-proven).
__global__ void scatter_atomic_kernel(const float* __restrict__ feat,
                                      const int* __restrict__ src,
                                      const int* __restrict__ dst,
                                      float* __restrict__ agg, int E) {
    int gid = blockIdx.x * blockDim.x + threadIdx.x;
    int e = gid >> 5;
    if (e >= E) return;
    int q = gid & 31;
    int s = src[e];
    int d = dst[e];
    const float4 v = ((const float4*)(feat + (size_t)s * F))[q];
    float* o = agg + (size_t)d * F + (q << 2);
    atomicAdd(o + 0, v.x);
    atomicAdd(o + 1, v.y);
    atomicAdd(o + 2, v.z);
    atomicAdd(o + 3, v.w);
}

// In-place h = relu(agg @ W^T + b), reading pre-transposed wT (coalesced).
__global__ __launch_bounds__(256) void linear_relu_kernel(
        float* __restrict__ h, const float* __restrict__ wT,
        const float* __restrict__ b, int N) {
    __shared__ __align__(16) float sA[ROWS2][132];
    const int tid = threadIdx.x;
    const int row0 = blockIdx.x * ROWS2;

    for (int i = tid; i < ROWS2 * 32; i += 256) {
        int r = i >> 5, q = i & 31;
        int gr = row0 + r;
        float4 v = make_float4(0.f, 0.f, 0.f, 0.f);
        if (gr < N) v = ((const float4*)(h + (size_t)gr * F))[q];
        *((float4*)&sA[r][q << 2]) = v;
    }
    __syncthreads();

    const int tr = tid >> 5;
    const int tc = tid & 31;
    float acc[4][4];
#pragma unroll
    for (int i = 0; i < 4; ++i)
#pragma unroll
        for (int j = 0; j < 4; ++j) acc[i][j] = 0.f;

    const float4* wT4 = (const float4*)wT;
    for (int k = 0; k < F; k += 4) {
        const float4 w0 = wT4[(k + 0) * 32 + tc];
        const float4 w1 = wT4[(k + 1) * 32 + tc];
        const float4 w2 = wT4[(k + 2) * 32 + tc];
        const float4 w3 = wT4[(k + 3) * 32 + tc];
#pragma unroll
        for (int i = 0; i < 4; ++i) {
            const float4 a = *(const float4*)&sA[tr * 4 + i][k];
            acc[i][0] += a.x * w0.x + a.y * w1.x + a.z * w2.x + a.w * w3.x;
            acc[i][1] += a.x * w0.y + a.y * w1.y + a.z * w2.y + a.w * w3.y;
            acc[i][2] += a.x * w0.z + a.y * w1.z + a.z * w2.z + a.w * w3.z;
            acc[i][3] += a.x * w0.w + a.y * w1.w + a.z * w2.w + a.w * w3.w;
        }
    }

    const float4 bias = ((const float4*)b)[tc];
#pragma unroll
    for (int i = 0; i < 4; ++i) {
        int gr = row0 + tr * 4 + i;
        if (gr < N) {
            float4 o;
            o.x = fmaxf(acc[i][0] + bias.x, 0.f);
            o.y = fmaxf(acc[i][1] + bias.y, 0.f);
            o.z = fmaxf(acc[i][2] + bias.z, 0.f);
            o.w = fmaxf(acc[i][3] + bias.w, 0.f);
            ((float4*)(h + (size_t)gr * F))[tc] = o;
        }
    }
}

// Tier-3 linear: reads W directly, 64-row tile.
__global__ __launch_bounds__(256) void linear_relu_w_kernel(
        float* __restrict__ h, const float* __restrict__ W,
        const float* __restrict__ b, int N) {
    __shared__ __align__(16) float sA[64][132];
    const int tid = threadIdx.x;
    const int row0 = blockIdx.x * 64;

    for (int i = tid; i < 64 * 32; i += 256) {
        int r = i >> 5, q = i & 31;
        int gr = row0 + r;
        float4 v = make_float4(0.f, 0.f, 0.f, 0.f);
        if (gr < N) v = ((const float4*)(h + (size_t)gr * F))[q];
        *((float4*)&sA[r][q << 2]) = v;
    }
    __syncthreads();

    const int tr = tid >> 5;
    const int tc = tid & 31;
    float acc[8][4];
#pragma unroll
    for (int i = 0; i < 8; ++i)
#pragma unroll
        for (int j = 0; j < 4; ++j) acc[i][j] = 0.f;

    const float* Wr0 = W + (size_t)(tc * 4 + 0) * F;
    const float* Wr1 = W + (size_t)(tc * 4 + 1) * F;
    const float* Wr2 = W + (size_t)(tc * 4 + 2) * F;
    const float* Wr3 = W + (size_t)(tc * 4 + 3) * F;

    for (int k = 0; k < F; k += 4) {
        const float4 w0 = *(const float4*)&Wr0[k];
        const float4 w1 = *(const float4*)&Wr1[k];
        const float4 w2 = *(const float4*)&Wr2[k];
        const float4 w3 = *(const float4*)&Wr3[k];
#pragma unroll
        for (int i = 0; i < 8; ++i) {
            const float4 a = *(const float4*)&sA[tr * 8 + i][k];
            acc[i][0] += a.x * w0.x + a.y * w0.y + a.z * w0.z + a.w * w0.w;
            acc[i][1] += a.x * w1.x + a.y * w1.y + a.z * w1.z + a.w * w1.w;
            acc[i][2] += a.x * w2.x + a.y * w2.y + a.z * w2.z + a.w * w2.w;
            acc[i][3] += a.x * w3.x + a.y * w3.y + a.z * w3.z + a.w * w3.w;
        }
    }

    const float4 bias = ((const float4*)b)[tc];
#pragma unroll
    for (int i = 0; i < 8; ++i) {
        int gr = row0 + tr * 8 + i;
        if (gr < N) {
            float4 o;
            o.x = fmaxf(acc[i][0] + bias.x, 0.f);
            o.y = fmaxf(acc[i][1] + bias.y, 0.f);
            o.z = fmaxf(acc[i][2] + bias.z, 0.f);
            o.w = fmaxf(acc[i][3] + bias.w, 0.f);
            ((float4*)(h + (size_t)gr * F))[tc] = o;
        }
    }
}

extern "C" void kernel_launch(void* const* d_in, const int* in_sizes, int n_in,
                              void* d_out, int out_size, void* d_ws, size_t ws_size,
                              hipStream_t stream) {
    const float* feat = (const float*)d_in[0];
    const int*   src  = (const int*)d_in[1];
    const int*   dst  = (const int*)d_in[2];
    const float* W    = (const float*)d_in[3];
    const float* b    = (const float*)d_in[4];
    float* out = (float*)d_out;

    const int N = in_sizes[0] / F;   // 50000
    const int E = in_sizes[1];       // 800000
    const int NB = (N + SCAN_TILE - 1) / SCAN_TILE;  // 49 (<=256)

    // ws layout (4B elems): counts[N] | offsets[N+1] | cursor[N] | blockSums[256]
    //   | qhead[8] | ssrc[E] | pad | wT[F*F] | featC[N*F]
    const size_t ints_before = (size_t)N + (N + 1) + N + 256 + 8 + E;
    const size_t wT_off = (ints_before + 3) & ~(size_t)3;
    const size_t featC_off = wT_off + (size_t)F * F;
    const size_t ws_tier1 = (featC_off + (size_t)N * F) * sizeof(int);
    const size_t ws_tier2 = (wT_off + (size_t)F * F) * sizeof(int);

    if (ws_size >= ws_tier2 && NB <= 256) {
        int* counts    = (int*)d_ws;
        int* offsets   = counts + N;
        int* cursor    = offsets + (N + 1);
        int* blockSums = cursor + N;
        int* qhead     = blockSums + 256;
        int* ssrc      = qhead + 8;
        float* wT      = (float*)d_ws + wT_off;
        float* featC   = (float*)d_ws + featC_off;
        const bool tier1 = (ws_size >= ws_tier1);

        transpose_w_kernel<<<64, 256, 0, stream>>>(W, wT);
        if (tier1)
            reorder_feat_kernel<<<(N * 32 + 255) / 256, 256, 0, stream>>>(feat, featC, N);
        zero_int_kernel<<<(N + 255) / 256, 256, 0, stream>>>(counts, N);
        hist_kernel<<<(E + 255) / 256, 256, 0, stream>>>(dst, counts, E);
        scan1_kernel<<<NB, 256, 0, stream>>>(counts, offsets, blockSums, N);
        scan2_kernel<<<1, 256, 0, stream>>>(blockSums, offsets, qhead, NB, N);
        scan3_kernel<<<(N + 255) / 256, 256, 0, stream>>>(offsets, cursor, blockSums, N);
        place_kernel<<<(E + 255) / 256, 256, 0, stream>>>(src, dst, cursor, ssrc, E);
        if (tier1)
            agg_xcd_kernel<<<2048, 256, 0, stream>>>(featC, ssrc, offsets, qhead, out, N);
        else
            agg_kernel<<<2048, 256, 0, stream>>>(feat, ssrc, offsets, out, N);
        linear_relu_kernel<<<(N + ROWS2 - 1) / ROWS2, 256, 0, stream>>>(out, wT, b, N);
    } else {
        const int n4 = N * (F / 4);
        zero_f4_kernel<<<(n4 + 255) / 256, 256, 0, stream>>>((float4*)out, n4);
        const int sthreads = E * 32;
        scatter_atomic_kernel<<<(sthreads + 255) / 256, 256, 0, stream>>>(feat, src, dst, out, E);
        linear_relu_w_kernel<<<(N + 63) / 64, 256, 0, stream>>>(out, W, b, N);
    }
}

// Round 11
// 270.472 us; speedup vs baseline: 1.8997x; 1.8997x over previous
//
#include <hip/hip_runtime.h>

#define F 128
#define SCAN_TILE 1024

__global__ void zero_f4_kernel(float4* __restrict__ out, int n4) {
    int i = blockIdx.x * blockDim.x + threadIdx.x;
    if (i < n4) out[i] = make_float4(0.f, 0.f, 0.f, 0.f);
}

// blocks [0,64): wT[k][o] = W[o][k];  blocks [64,...): zero counts
__global__ void init_kernel(const float* __restrict__ W, float* __restrict__ wT,
                            int* __restrict__ counts, int N) {
    int b = blockIdx.x;
    if (b < 64) {
        int i = b * 256 + threadIdx.x;
        int o = i >> 7, k = i & 127;
        wT[k * F + o] = W[i];
    } else {
        int i = (b - 64) * 256 + threadIdx.x;
        if (i < N) counts[i] = 0;
    }
}

__global__ void hist_kernel(const int* __restrict__ dst, int* __restrict__ counts, int E) {
    int e = blockIdx.x * blockDim.x + threadIdx.x;
    if (e < E) atomicAdd(&counts[dst[e]], 1);
}

__global__ __launch_bounds__(256) void scan1_kernel(const int* __restrict__ counts,
                                                    int* __restrict__ offsets,
                                                    int* __restrict__ blockSums, int N) {
    __shared__ int lds[256];
    const int tid = threadIdx.x;
    const int i0 = blockIdx.x * SCAN_TILE + tid * 4;
    int v[4];
    int s = 0;
#pragma unroll
    for (int j = 0; j < 4; ++j) {
        int i = i0 + j;
        v[j] = (i < N) ? counts[i] : 0;
        s += v[j];
    }
    lds[tid] = s;
    __syncthreads();
    for (int off = 1; off < 256; off <<= 1) {
        int t = (tid >= off) ? lds[tid - off] : 0;
        __syncthreads();
        lds[tid] += t;
        __syncthreads();
    }
    int excl = lds[tid] - s;
#pragma unroll
    for (int j = 0; j < 4; ++j) {
        int i = i0 + j;
        if (i < N) offsets[i] = excl;
        excl += v[j];
    }
    if (tid == 255) blockSums[blockIdx.x] = lds[255];
}

__global__ __launch_bounds__(256) void scan2_kernel(int* __restrict__ blockSums,
                                                    int* __restrict__ offsets, int NB, int N) {
    __shared__ int lds[256];
    const int tid = threadIdx.x;
    int s = (tid < NB) ? blockSums[tid] : 0;
    lds[tid] = s;
    __syncthreads();
    for (int off = 1; off < 256; off <<= 1) {
        int t = (tid >= off) ? lds[tid - off] : 0;
        __syncthreads();
        lds[tid] += t;
        __syncthreads();
    }
    if (tid < NB) blockSums[tid] = lds[tid] - s;
    if (tid == 255) offsets[N] = lds[255];
}

__global__ __launch_bounds__(256) void scan3_kernel(int* __restrict__ offsets,
                                                    int* __restrict__ cursor,
                                                    const int* __restrict__ blockSums, int N) {
    int i = blockIdx.x * blockDim.x + threadIdx.x;
    if (i < N) {
        int o = offsets[i] + blockSums[i / SCAN_TILE];
        offsets[i] = o;
        cursor[i] = o;
    }
}

__global__ void place_kernel(const int* __restrict__ src, const int* __restrict__ dst,
                             int* __restrict__ cursor, int* __restrict__ ssrc, int E) {
    int e = blockIdx.x * blockDim.x + threadIdx.x;
    if (e < E) {
        int pos = atomicAdd(&cursor[dst[e]], 1);
        ssrc[pos] = src[e];
    }
}

// Fused aggregate + linear + relu. Block owns 32 nodes:
//  Phase 1 (R7-proven gather): each wave aggregates 8 nodes, half-wave per
//  edge, float4/lane, 4-edge unroll; row lands in sA (the GEMM's A-tile).
//  Phase 2: 32x128 @ wT (coalesced) with bias+relu, write final out.
// LDS 16.9 KB -> all 1563 blocks co-resident (~6/CU); gather stalls of some
// blocks overlap GEMM VALU of others.
__global__ __launch_bounds__(256) void agg_linear_kernel(
        const float* __restrict__ feat, const int* __restrict__ ssrc,
        const int* __restrict__ offs, const float* __restrict__ wT,
        const float* __restrict__ b, float* __restrict__ out, int N) {
    __shared__ __align__(16) float sA[32][132];
    const int tid = threadIdx.x;
    const int wave = tid >> 6;
    const int lane = tid & 63;
    const int half = lane >> 5;
    const int q = lane & 31;
    const int row0 = blockIdx.x * 32;
    const float4* feat4 = (const float4*)feat;

    // Phase 1: aggregate rows row0+wave*8 .. +8 into sA.
    for (int r = wave * 8; r < wave * 8 + 8; ++r) {
        const int v = row0 + r;
        float ax = 0.f, ay = 0.f, az = 0.f, aw = 0.f;
        if (v < N) {
            const int s0 = offs[v], s1 = offs[v + 1];
            int e = s0 + half;
            for (; e + 6 < s1; e += 8) {
                int i0 = ssrc[e], i1 = ssrc[e + 2], i2 = ssrc[e + 4], i3 = ssrc[e + 6];
                const float4 f0 = feat4[(size_t)i0 * 32 + q];
                const float4 f1 = feat4[(size_t)i1 * 32 + q];
                const float4 f2 = feat4[(size_t)i2 * 32 + q];
                const float4 f3 = feat4[(size_t)i3 * 32 + q];
                ax += (f0.x + f1.x) + (f2.x + f3.x);
                ay += (f0.y + f1.y) + (f2.y + f3.y);
                az += (f0.z + f1.z) + (f2.z + f3.z);
                aw += (f0.w + f1.w) + (f2.w + f3.w);
            }
            for (; e < s1; e += 2) {
                const float4 f0 = feat4[(size_t)ssrc[e] * 32 + q];
                ax += f0.x; ay += f0.y; az += f0.z; aw += f0.w;
            }
        }
        ax += __shfl_xor(ax, 32);
        ay += __shfl_xor(ay, 32);
        az += __shfl_xor(az, 32);
        aw += __shfl_xor(aw, 32);
        if (half == 0) {
            float4 r4; r4.x = ax; r4.y = ay; r4.z = az; r4.w = aw;
            *(float4*)&sA[r][q << 2] = r4;
        }
    }
    __syncthreads();

    // Phase 2: h = relu(sA @ W^T + b) via coalesced wT reads.
    const int tr = tid >> 5;   // 0..7 -> rows tr*4..tr*4+3
    const int tc = tid & 31;   // cols tc*4..tc*4+3
    float acc[4][4];
#pragma unroll
    for (int i = 0; i < 4; ++i)
#pragma unroll
        for (int j = 0; j < 4; ++j) acc[i][j] = 0.f;

    const float4* wT4 = (const float4*)wT;
    for (int k = 0; k < F; k += 4) {
        const float4 w0 = wT4[(k + 0) * 32 + tc];
        const float4 w1 = wT4[(k + 1) * 32 + tc];
        const float4 w2 = wT4[(k + 2) * 32 + tc];
        const float4 w3 = wT4[(k + 3) * 32 + tc];
#pragma unroll
        for (int i = 0; i < 4; ++i) {
            const float4 a = *(const float4*)&sA[tr * 4 + i][k];
            acc[i][0] += a.x * w0.x + a.y * w1.x + a.z * w2.x + a.w * w3.x;
            acc[i][1] += a.x * w0.y + a.y * w1.y + a.z * w2.y + a.w * w3.y;
            acc[i][2] += a.x * w0.z + a.y * w1.z + a.z * w2.z + a.w * w3.z;
            acc[i][3] += a.x * w0.w + a.y * w1.w + a.z * w2.w + a.w * w3.w;
        }
    }

    const float4 bias = ((const float4*)b)[tc];
#pragma unroll
    for (int i = 0; i < 4; ++i) {
        int gr = row0 + tr * 4 + i;
        if (gr < N) {
            float4 o;
            o.x = fmaxf(acc[i][0] + bias.x, 0.f);
            o.y = fmaxf(acc[i][1] + bias.y, 0.f);
            o.z = fmaxf(acc[i][2] + bias.z, 0.f);
            o.w = fmaxf(acc[i][3] + bias.w, 0.f);
            ((float4*)(out + (size_t)gr * F))[tc] = o;
        }
    }
}

// Tier-3 fallback: direct fp32 atomic scatter (R1-proven).
__global__ void scatter_atomic_kernel(const float* __restrict__ feat,
                                      const int* __restrict__ src,
                                      const int* __restrict__ dst,
                                      float* __restrict__ agg, int E) {
    int gid = blockIdx.x * blockDim.x + threadIdx.x;
    int e = gid >> 5;
    if (e >= E) return;
    int q = gid & 31;
    int s = src[e];
    int d = dst[e];
    const float4 v = ((const float4*)(feat + (size_t)s * F))[q];
    float* o = agg + (size_t)d * F + (q << 2);
    atomicAdd(o + 0, v.x);
    atomicAdd(o + 1, v.y);
    atomicAdd(o + 2, v.z);
    atomicAdd(o + 3, v.w);
}

// Tier-3 linear: reads W directly, in-place on out, 64-row tile.
__global__ __launch_bounds__(256) void linear_relu_w_kernel(
        float* __restrict__ h, const float* __restrict__ W,
        const float* __restrict__ b, int N) {
    __shared__ __align__(16) float sA[64][132];
    const int tid = threadIdx.x;
    const int row0 = blockIdx.x * 64;

    for (int i = tid; i < 64 * 32; i += 256) {
        int r = i >> 5, q = i & 31;
        int gr = row0 + r;
        float4 v = make_float4(0.f, 0.f, 0.f, 0.f);
        if (gr < N) v = ((const float4*)(h + (size_t)gr * F))[q];
        *((float4*)&sA[r][q << 2]) = v;
    }
    __syncthreads();

    const int tr = tid >> 5;
    const int tc = tid & 31;
    float acc[8][4];
#pragma unroll
    for (int i = 0; i < 8; ++i)
#pragma unroll
        for (int j = 0; j < 4; ++j) acc[i][j] = 0.f;

    const float* Wr0 = W + (size_t)(tc * 4 + 0) * F;
    const float* Wr1 = W + (size_t)(tc * 4 + 1) * F;
    const float* Wr2 = W + (size_t)(tc * 4 + 2) * F;
    const float* Wr3 = W + (size_t)(tc * 4 + 3) * F;

    for (int k = 0; k < F; k += 4) {
        const float4 w0 = *(const float4*)&Wr0[k];
        const float4 w1 = *(const float4*)&Wr1[k];
        const float4 w2 = *(const float4*)&Wr2[k];
        const float4 w3 = *(const float4*)&Wr3[k];
#pragma unroll
        for (int i = 0; i < 8; ++i) {
            const float4 a = *(const float4*)&sA[tr * 8 + i][k];
            acc[i][0] += a.x * w0.x + a.y * w0.y + a.z * w0.z + a.w * w0.w;
            acc[i][1] += a.x * w1.x + a.y * w1.y + a.z * w1.z + a.w * w1.w;
            acc[i][2] += a.x * w2.x + a.y * w2.y + a.z * w2.z + a.w * w2.w;
            acc[i][3] += a.x * w3.x + a.y * w3.y + a.z * w3.z + a.w * w3.w;
        }
    }

    const float4 bias = ((const float4*)b)[tc];
#pragma unroll
    for (int i = 0; i < 8; ++i) {
        int gr = row0 + tr * 8 + i;
        if (gr < N) {
            float4 o;
            o.x = fmaxf(acc[i][0] + bias.x, 0.f);
            o.y = fmaxf(acc[i][1] + bias.y, 0.f);
            o.z = fmaxf(acc[i][2] + bias.z, 0.f);
            o.w = fmaxf(acc[i][3] + bias.w, 0.f);
            ((float4*)(h + (size_t)gr * F))[tc] = o;
        }
    }
}

extern "C" void kernel_launch(void* const* d_in, const int* in_sizes, int n_in,
                              void* d_out, int out_size, void* d_ws, size_t ws_size,
                              hipStream_t stream) {
    const float* feat = (const float*)d_in[0];
    const int*   src  = (const int*)d_in[1];
    const int*   dst  = (const int*)d_in[2];
    const float* W    = (const float*)d_in[3];
    const float* b    = (const float*)d_in[4];
    float* out = (float*)d_out;

    const int N = in_sizes[0] / F;   // 50000
    const int E = in_sizes[1];       // 800000
    const int NB = (N + SCAN_TILE - 1) / SCAN_TILE;  // 49 (<=256)

    // ws layout (4B elems): counts[N] | offsets[N+1] | cursor[N] | blockSums[256]
    //   | ssrc[E] | pad | wT[F*F]
    const size_t ints_before = (size_t)N + (N + 1) + N + 256 + E;
    const size_t wT_off = (ints_before + 3) & ~(size_t)3;
    const size_t ws_needed = (wT_off + (size_t)F * F) * sizeof(int);

    if (ws_size >= ws_needed && NB <= 256) {
        int* counts    = (int*)d_ws;
        int* offsets   = counts + N;
        int* cursor    = offsets + (N + 1);
        int* blockSums = cursor + N;
        int* ssrc      = blockSums + 256;
        float* wT      = (float*)d_ws + wT_off;

        const int zb = (N + 255) / 256;                 // 196
        init_kernel<<<64 + zb, 256, 0, stream>>>(W, wT, counts, N);
        hist_kernel<<<(E + 255) / 256, 256, 0, stream>>>(dst, counts, E);
        scan1_kernel<<<NB, 256, 0, stream>>>(counts, offsets, blockSums, N);
        scan2_kernel<<<1, 256, 0, stream>>>(blockSums, offsets, NB, N);
        scan3_kernel<<<(N + 255) / 256, 256, 0, stream>>>(offsets, cursor, blockSums, N);
        place_kernel<<<(E + 255) / 256, 256, 0, stream>>>(src, dst, cursor, ssrc, E);
        agg_linear_kernel<<<(N + 31) / 32, 256, 0, stream>>>(feat, ssrc, offsets, wT, b, out, N);
    } else {
        const int n4 = N * (F / 4);
        zero_f4_kernel<<<(n4 + 255) / 256, 256, 0, stream>>>((float4*)out, n4);
        const int sthreads = E * 32;
        scatter_atomic_kernel<<<(sthreads + 255) / 256, 256, 0, stream>>>(feat, src, dst, out, E);
        linear_relu_w_kernel<<<(N + 63) / 64, 256, 0, stream>>>(out, W, b, N);
    }
}